// Round 8
// baseline (291.492 us; speedup 1.0000x reference)
//
#include <hip/hip_runtime.h>
#include <stdint.h>

typedef unsigned short ushort_t;

#define T_SEQ 2048
#define BATCH 4
#define NHEAD 12
#define CEMB 768
#define HDIM 64
#define C3 2304

// ---------- bf16 helpers (HW convert, RNE) ----------
__device__ __forceinline__ ushort_t f2b_hw(float f) {
  union { __bf16 h; ushort_t u; } p;
  p.h = (__bf16)f;
  return p.u;
}
__device__ __forceinline__ uint32_t pkbf16(float lo, float hi) {
  union { __bf16 h[2]; uint32_t u; } p;
  p.h[0] = (__bf16)lo; p.h[1] = (__bf16)hi;
  return p.u;
}

// ---------- async global->LDS 16B ----------
typedef __attribute__((address_space(3))) unsigned int lds_u32_t;
typedef const __attribute__((address_space(1))) unsigned int glb_u32_t;
__device__ __forceinline__ void async_cp16(const void* g, void* l) {
  __builtin_amdgcn_global_load_lds((glb_u32_t*)g, (lds_u32_t*)l, 16, 0, 0);
}

// ---------- fp32 -> bf16 bulk convert (8 elems/thread) ----------
__global__ __launch_bounds__(256) void cvt_x_k(const float* __restrict__ in,
                                               ushort_t* __restrict__ out) {
  const int i = blockIdx.x * 256 + threadIdx.x;
  float4 a = ((const float4*)in)[2 * i];
  float4 b = ((const float4*)in)[2 * i + 1];
  uint4 v;
  v.x = pkbf16(a.x, a.y); v.y = pkbf16(a.z, a.w);
  v.z = pkbf16(b.x, b.y); v.w = pkbf16(b.z, b.w);
  ((uint4*)out)[i] = v;
}

// ---------- fused transpose + fp32->bf16: out[c][r] = bf16(in[r][c]) ----------
__global__ void transpose_cvt_k(const float* __restrict__ in, ushort_t* __restrict__ out,
                                int R, int C) {
  __shared__ ushort_t tile[32][33];
  const int c0 = blockIdx.x * 32, r0 = blockIdx.y * 32;
  for (int i = threadIdx.y; i < 32; i += 8)
    tile[i][threadIdx.x] = f2b_hw(in[(size_t)(r0 + i) * C + c0 + threadIdx.x]);
  __syncthreads();
  for (int i = threadIdx.y; i < 32; i += 8)
    out[(size_t)(c0 + i) * R + r0 + threadIdx.x] = tile[threadIdx.x][i];
}

// ---------- MFMA GEMM: C[M,N] = A[M,K] * Bt[N,K]^T + bias ----------
typedef __bf16 bf16x8 __attribute__((ext_vector_type(8)));
typedef float f32x4 __attribute__((ext_vector_type(4)));

template <bool OUTF, int BM>  // BM = M-tile (128 or 64), N-tile fixed 128
__global__ __launch_bounds__(256) void gemm_bt(const ushort_t* __restrict__ A,
                                               const ushort_t* __restrict__ Bt,
                                               const float* __restrict__ bias,
                                               void* __restrict__ Cv,
                                               int M, int N, int K) {
  constexpr int TM = BM / 32;  // m-frags per wave
  __shared__ ushort_t As[BM * 32];
  __shared__ ushort_t Bs[128 * 32];
  const int tid = threadIdx.x;
  const int m0 = blockIdx.y * BM, n0 = blockIdx.x * 128;
  const int wid = tid >> 6, lane = tid & 63;
  const int quad = lane >> 4, l15 = lane & 15;
  const int wm = (wid >> 1) * (BM / 2), wn = (wid & 1) * 64;
  f32x4 acc[TM][4] = {};

  const int e0 = tid * 8;  // lane-linear 16B chunks (global_load_lds requirement)
  const int r0s = e0 >> 5, c0s = e0 & 31;
  const int e1 = e0 + 2048;
  const int r1s = e1 >> 5, c1s = e1 & 31;

  for (int k0 = 0; k0 < K; k0 += 32) {
    __syncthreads();
    async_cp16(&A[(size_t)(m0 + r0s) * K + k0 + c0s], &As[e0]);
    if constexpr (BM == 128)
      async_cp16(&A[(size_t)(m0 + r1s) * K + k0 + c1s], &As[e1]);
    async_cp16(&Bt[(size_t)(n0 + r0s) * K + k0 + c0s], &Bs[e0]);
    async_cp16(&Bt[(size_t)(n0 + r1s) * K + k0 + c1s], &Bs[e1]);
    __syncthreads();
    bf16x8 af[TM], bfr[4];
#pragma unroll
    for (int t = 0; t < TM; t++)
      af[t] = *(const bf16x8*)&As[(wm + t * 16 + l15) * 32 + quad * 8];
#pragma unroll
    for (int t = 0; t < 4; t++)
      bfr[t] = *(const bf16x8*)&Bs[(wn + t * 16 + l15) * 32 + quad * 8];
#pragma unroll
    for (int tm = 0; tm < TM; tm++)
#pragma unroll
      for (int tn = 0; tn < 4; tn++)
        acc[tm][tn] = __builtin_amdgcn_mfma_f32_16x16x32_bf16(af[tm], bfr[tn], acc[tm][tn], 0, 0, 0);
  }

#pragma unroll
  for (int tm = 0; tm < TM; tm++) {
    const int row = m0 + wm + tm * 16 + quad * 4;
#pragma unroll
    for (int tn = 0; tn < 4; tn++) {
      const int col = n0 + wn + tn * 16 + l15;
      const float bv = bias[col];
#pragma unroll
      for (int rr = 0; rr < 4; rr++) {
        if constexpr (OUTF)
          ((float*)Cv)[(size_t)(row + rr) * N + col] = acc[tm][tn][rr] + bv;
        else
          ((ushort_t*)Cv)[(size_t)(row + rr) * N + col] = f2b_hw(acc[tm][tn][rr] + bv);
      }
    }
  }
}

// ---------- MFMA flash attention (S^T / O^T form), causal, balanced ----------
// Block s in [0,16); wave w owns 32-q strip at qw = w*512 + s*32.
// S^T = K*Q^T -> C-layout (q=l15, key=quad*4+r): softmax rows per-lane.
// PV as O^T = V^T * P^T: alpha/l indexed by l15 -> no broadcast shuffles.
// Prefetch of next K/V tile issued AFTER the staging barrier so the
// compiler's vmcnt(0)-before-barrier drain lands after the compute phase.
#define KPAD 40  // K LDS row stride: 80 B, 16B-aligned
#define PSTR 72  // Vt/Plds row stride: 144 B, 16B-aligned

__global__ __launch_bounds__(256) void attn_mfma_k(const ushort_t* __restrict__ qkv,
                                                   ushort_t* __restrict__ y) {
  __shared__ ushort_t Ksm[2 * 64 * KPAD];  // [d-half][key][KPAD]
  __shared__ ushort_t Vt[64 * PSTR];       // [d][key]
  __shared__ ushort_t Plds[4][32 * PSTR];  // per-wave [q_local][key]

  const int s = blockIdx.x;
  const int h = blockIdx.y, b = blockIdx.z;
  const int tid = threadIdx.x;
  const int w = tid >> 6, lane = tid & 63;
  const int quad = lane >> 4, l15 = lane & 15;
  const int qw = w * 512 + s * 32;

  // Q fragments (B-operand): [q-subtile][d-half]
  bf16x8 qB[2][2];
#pragma unroll
  for (int n = 0; n < 2; n++)
#pragma unroll
    for (int kb = 0; kb < 2; kb++)
      qB[n][kb] = *(const bf16x8*)&qkv[((size_t)(b * T_SEQ + qw + n * 16 + l15)) * C3 +
                                       h * HDIM + kb * 32 + quad * 8];

  f32x4 o2[4][2] = {};  // O^T: [d-sub][q-sub], row=d(quad*4+r), col=q(l15)
  float m_i[2] = {-3e38f, -3e38f}, l_i[2] = {0.f, 0.f};

  // hoisted LDS offsets
  int koffA[4], koffB[4], voff[4], poffR[2], poffW[2];
#pragma unroll
  for (int m = 0; m < 4; m++) {
    koffA[m] = (m * 16 + l15) * KPAD + quad * 8;
    koffB[m] = koffA[m] + 64 * KPAD;
  }
#pragma unroll
  for (int nd = 0; nd < 4; nd++) voff[nd] = (nd * 16 + l15) * PSTR + quad * 8;
#pragma unroll
  for (int n = 0; n < 2; n++) {
    poffR[n] = (n * 16 + l15) * PSTR + quad * 8;
    poffW[n] = (n * 16 + l15) * PSTR + quad * 4;
  }

  // staging maps
  const int krow = tid >> 2, kseg = tid & 3;
  const int vpair = tid & 31, vd0 = (tid >> 5) * 8;
  ushort_t* kdst0 = &Ksm[krow * KPAD + kseg * 8];
  ushort_t* kdst1 = kdst0 + 64 * KPAD;

  const int nkt = ((1567 + s * 32) >> 6) + 1;  // 25..32
  const size_t step = (size_t)64 * C3;
  const ushort_t* kp = qkv + ((size_t)(b * T_SEQ) + krow) * C3 + CEMB + h * HDIM + kseg * 8;
  const ushort_t* vp = qkv + ((size_t)(b * T_SEQ) + 2 * vpair) * C3 + 2 * CEMB + h * HDIM + vd0;
  uint4 pK0 = *(const uint4*)kp, pK1 = *(const uint4*)(kp + 32);
  uint4 pV0 = *(const uint4*)vp, pV1 = *(const uint4*)(vp + C3);

  const float C2 = 0.18033688011112042f;  // 0.125 * log2(e)

  for (int kt = 0; kt < nkt; ++kt) {
    __syncthreads();  // prior compute reads done; prior prefetch drained here
    // ---- commit prefetched tile ----
    *(uint4*)kdst0 = pK0;
    *(uint4*)kdst1 = pK1;
    {
      union { uint32_t u[4]; uint4 v; } a, c;
      a.v = pV0; c.v = pV1;
#pragma unroll
      for (int j = 0; j < 8; j++) {
        uint32_t pk = __builtin_amdgcn_perm(c.u[j >> 1], a.u[j >> 1],
                                            (j & 1) ? 0x07060302u : 0x05040100u);
        *(uint32_t*)&Vt[(vd0 + j) * PSTR + 2 * vpair] = pk;
      }
    }
    __syncthreads();  // staging visible
    // ---- issue next prefetch (in flight across the compute phase) ----
    if (kt + 1 < nkt) {
      kp += step; vp += step;
      pK0 = *(const uint4*)kp; pK1 = *(const uint4*)(kp + 32);
      pV0 = *(const uint4*)vp; pV1 = *(const uint4*)(vp + C3);
    }

    if (kt * 64 <= qw + 31) {
      // ---- S^T = K*Q^T ----
      bf16x8 kA[4][2];
#pragma unroll
      for (int m = 0; m < 4; m++) {
        kA[m][0] = *(const bf16x8*)&Ksm[koffA[m]];
        kA[m][1] = *(const bf16x8*)&Ksm[koffB[m]];
      }
      f32x4 st[4][2] = {};  // [key-sub][q-sub]
#pragma unroll
      for (int m = 0; m < 4; m++)
#pragma unroll
        for (int n = 0; n < 2; n++) {
          st[m][n] = __builtin_amdgcn_mfma_f32_16x16x32_bf16(kA[m][0], qB[n][0], st[m][n], 0, 0, 0);
          st[m][n] = __builtin_amdgcn_mfma_f32_16x16x32_bf16(kA[m][1], qB[n][1], st[m][n], 0, 0, 0);
        }

      // ---- causal mask (near diagonal only) ----
      if (kt * 64 + 63 > qw) {
#pragma unroll
        for (int m = 0; m < 4; m++)
#pragma unroll
          for (int r = 0; r < 4; r++) {
            const int keyg = kt * 64 + m * 16 + quad * 4 + r;
#pragma unroll
            for (int n = 0; n < 2; n++) {
              const int qg = qw + n * 16 + l15;
              if (keyg > qg) st[m][n][r] = -3e38f;
            }
          }
      }

      // ---- online softmax (q on l15; keys in-lane + cross-quad) ----
      float al[2];
#pragma unroll
      for (int n = 0; n < 2; n++) {
        float mx = st[0][n][0];
#pragma unroll
        for (int m = 0; m < 4; m++)
#pragma unroll
          for (int r = 0; r < 4; r++) mx = fmaxf(mx, st[m][n][r]);
        mx = fmaxf(mx, __shfl_xor(mx, 16, 64));
        mx = fmaxf(mx, __shfl_xor(mx, 32, 64));
        const float mn = fmaxf(m_i[n], mx);
        al[n] = exp2f((m_i[n] - mn) * C2);
        m_i[n] = mn;
        const float mnc = mn * C2;
        float ls = 0.f;
#pragma unroll
        for (int m = 0; m < 4; m++)
#pragma unroll
          for (int r = 0; r < 4; r++) {
            float p = exp2f(fmaf(st[m][n][r], C2, -mnc));
            st[m][n][r] = p;
            ls += p;
          }
        ls += __shfl_xor(ls, 16, 64);
        ls += __shfl_xor(ls, 32, 64);
        l_i[n] = l_i[n] * al[n] + ls;
      }

      // ---- P -> LDS (packed b64) + O^T rescale (alpha per-lane, no shfl) ----
#pragma unroll
      for (int n = 0; n < 2; n++) {
#pragma unroll
        for (int m = 0; m < 4; m++) {
          uint2 pk;
          pk.x = pkbf16(st[m][n][0], st[m][n][1]);
          pk.y = pkbf16(st[m][n][2], st[m][n][3]);
          *(uint2*)&Plds[w][poffW[n] + m * 16] = pk;
        }
#pragma unroll
        for (int nd = 0; nd < 4; nd++)
#pragma unroll
          for (int r = 0; r < 4; r++) o2[nd][n][r] *= al[n];
      }

      // in-wave DS ordering: P writes committed before cross-lane reads
      asm volatile("s_waitcnt lgkmcnt(0)" ::: "memory");

      // ---- O^T += V^T * P^T  (A=V^T, B=P) ----
      bf16x8 ap[2][2], bv[4][2];
#pragma unroll
      for (int n = 0; n < 2; n++)
#pragma unroll
        for (int kb = 0; kb < 2; kb++)
          ap[n][kb] = *(const bf16x8*)&Plds[w][poffR[n] + kb * 32];
#pragma unroll
      for (int nd = 0; nd < 4; nd++)
#pragma unroll
        for (int kb = 0; kb < 2; kb++)
          bv[nd][kb] = *(const bf16x8*)&Vt[voff[nd] + kb * 32];
#pragma unroll
      for (int nd = 0; nd < 4; nd++)
#pragma unroll
        for (int n = 0; n < 2; n++) {
          o2[nd][n] = __builtin_amdgcn_mfma_f32_16x16x32_bf16(bv[nd][0], ap[n][0], o2[nd][n], 0, 0, 0);
          o2[nd][n] = __builtin_amdgcn_mfma_f32_16x16x32_bf16(bv[nd][1], ap[n][1], o2[nd][n], 0, 0, 0);
        }
    }
  }

  // ---- epilogue: y[q][h*64+d] = O^T[d][q] / l, packed b64 stores ----
#pragma unroll
  for (int n = 0; n < 2; n++) {
    const float inv = 1.0f / l_i[n];
    const int qg = qw + n * 16 + l15;
    ushort_t* yp = y + ((size_t)(b * T_SEQ + qg)) * CEMB + h * HDIM + quad * 4;
#pragma unroll
    for (int nd = 0; nd < 4; nd++) {
      uint2 pk;
      pk.x = pkbf16(o2[nd][n][0] * inv, o2[nd][n][1] * inv);
      pk.y = pkbf16(o2[nd][n][2] * inv, o2[nd][n][3] * inv);
      *(uint2*)(yp + nd * 16) = pk;
    }
  }
}

// ---------- launcher ----------
extern "C" void kernel_launch(void* const* d_in, const int* in_sizes, int n_in,
                              void* d_out, int out_size, void* d_ws, size_t ws_size,
                              hipStream_t stream) {
  const float* x      = (const float*)d_in[0];  // [4,2048,768] fp32
  const float* w_attn = (const float*)d_in[1];  // [768,2304]
  const float* b_attn = (const float*)d_in[2];  // [2304]
  const float* w_proj = (const float*)d_in[3];  // [768,768]
  const float* b_proj = (const float*)d_in[4];  // [768]
  float* out = (float*)d_out;                   // [4,2048,768] fp32

  char* ws = (char*)d_ws;
  ushort_t* qkv = (ushort_t*)ws;                          // 8192*2304 bf16
  ushort_t* y   = qkv + (size_t)8192 * 2304;              // 8192*768
  ushort_t* xb  = y + (size_t)8192 * 768;                 // 8192*768 bf16 x
  ushort_t* wT  = xb + (size_t)8192 * 768;                // 2304*768 (w_attn^T)
  ushort_t* wpT = wT + (size_t)2304 * 768;                // 768*768  (w_proj^T)

  cvt_x_k<<<3072, 256, 0, stream>>>(x, xb);
  transpose_cvt_k<<<dim3(C3 / 32, CEMB / 32), dim3(32, 8), 0, stream>>>(w_attn, wT, CEMB, C3);
  transpose_cvt_k<<<dim3(CEMB / 32, CEMB / 32), dim3(32, 8), 0, stream>>>(w_proj, wpT, CEMB, CEMB);

  // qkv = x @ w_attn + b_attn   (M=8192, N=2304, K=768), bf16 out
  gemm_bt<false, 128><<<dim3(C3 / 128, 8192 / 128), 256, 0, stream>>>(xb, wT, b_attn, qkv, 8192, C3, CEMB);

  // MFMA flash attention -> y [B,T,C] bf16
  attn_mfma_k<<<dim3(16, NHEAD, BATCH), 256, 0, stream>>>(qkv, y);

  // out = y @ w_proj + b_proj   (M=8192, N=768, K=768), fp32 out; 64-row
  // M-tiles -> 768 blocks (3/CU) instead of 384 (1.5/CU half-idle).
  gemm_bt<true, 64><<<dim3(CEMB / 128, 8192 / 64), 256, 0, stream>>>(y, wpT, b_proj, out, 8192, CEMB, CEMB);
}

// Round 9
// 256.948 us; speedup vs baseline: 1.1344x; 1.1344x over previous
//
#include <hip/hip_runtime.h>
#include <stdint.h>

typedef unsigned short ushort_t;

#define T_SEQ 2048
#define BATCH 4
#define NHEAD 12
#define CEMB 768
#define HDIM 64
#define C3 2304

// ---------- bf16 helpers (HW convert, RNE) ----------
__device__ __forceinline__ ushort_t f2b_hw(float f) {
  union { __bf16 h; ushort_t u; } p;
  p.h = (__bf16)f;
  return p.u;
}
__device__ __forceinline__ uint32_t pkbf16(float lo, float hi) {
  union { __bf16 h[2]; uint32_t u; } p;
  p.h[0] = (__bf16)lo; p.h[1] = (__bf16)hi;
  return p.u;
}

// ---------- async global->LDS 16B ----------
typedef __attribute__((address_space(3))) unsigned int lds_u32_t;
typedef const __attribute__((address_space(1))) unsigned int glb_u32_t;
__device__ __forceinline__ void async_cp16(const void* g, void* l) {
  __builtin_amdgcn_global_load_lds((glb_u32_t*)g, (lds_u32_t*)l, 16, 0, 0);
}

// ---------- fused prep: cvt x -> bf16; transpose+cvt both weights ----------
// blocks [0,3072): cvt_x (8 elems/thread)
// blocks [3072,4800): transpose w_attn (768x2304 -> 2304x768), 32x32 tiles
// blocks [4800,5376): transpose w_proj (768x768), 32x32 tiles
__global__ __launch_bounds__(256) void prep_k(const float* __restrict__ x, ushort_t* __restrict__ xb,
                                              const float* __restrict__ wa, ushort_t* __restrict__ wT,
                                              const float* __restrict__ wp, ushort_t* __restrict__ wpT) {
  const int blk = blockIdx.x;
  const int tid = threadIdx.x;
  if (blk < 3072) {
    const int i = blk * 256 + tid;
    float4 a = ((const float4*)x)[2 * i];
    float4 b = ((const float4*)x)[2 * i + 1];
    uint4 v;
    v.x = pkbf16(a.x, a.y); v.y = pkbf16(a.z, a.w);
    v.z = pkbf16(b.x, b.y); v.w = pkbf16(b.z, b.w);
    ((uint4*)xb)[i] = v;
    return;
  }
  __shared__ ushort_t tile[32][33];
  const float* in; ushort_t* out; int R, C, bx, by;
  if (blk < 4800) {
    const int t = blk - 3072;
    in = wa; out = wT; R = CEMB; C = C3;
    bx = t % 72; by = t / 72;
  } else {
    const int t = blk - 4800;
    in = wp; out = wpT; R = CEMB; C = CEMB;
    bx = t % 24; by = t / 24;
  }
  const int tx = tid & 31, ty = tid >> 5;
  const int c0 = bx * 32, r0 = by * 32;
  for (int i = ty; i < 32; i += 8)
    tile[i][tx] = f2b_hw(in[(size_t)(r0 + i) * C + c0 + tx]);
  __syncthreads();
  for (int i = ty; i < 32; i += 8)
    out[(size_t)(c0 + i) * R + r0 + tx] = tile[tx][i];
}

// ---------- MFMA GEMM: C[M,N] = A[M,K] * Bt[N,K]^T + bias ----------
typedef __bf16 bf16x8 __attribute__((ext_vector_type(8)));
typedef float f32x4 __attribute__((ext_vector_type(4)));

template <bool OUTF, int BM>  // BM = M-tile (128 or 64), N-tile fixed 128
__global__ __launch_bounds__(256) void gemm_bt(const ushort_t* __restrict__ A,
                                               const ushort_t* __restrict__ Bt,
                                               const float* __restrict__ bias,
                                               void* __restrict__ Cv,
                                               int M, int N, int K) {
  constexpr int TM = BM / 32;
  __shared__ ushort_t As[BM * 32];
  __shared__ ushort_t Bs[128 * 32];
  const int tid = threadIdx.x;
  const int m0 = blockIdx.y * BM, n0 = blockIdx.x * 128;
  const int wid = tid >> 6, lane = tid & 63;
  const int quad = lane >> 4, l15 = lane & 15;
  const int wm = (wid >> 1) * (BM / 2), wn = (wid & 1) * 64;
  f32x4 acc[TM][4] = {};

  const int e0 = tid * 8;  // lane-linear 16B chunks
  const int r0s = e0 >> 5, c0s = e0 & 31;
  const int e1 = e0 + 2048;
  const int r1s = e1 >> 5, c1s = e1 & 31;

  for (int k0 = 0; k0 < K; k0 += 32) {
    __syncthreads();
    async_cp16(&A[(size_t)(m0 + r0s) * K + k0 + c0s], &As[e0]);
    if constexpr (BM == 128)
      async_cp16(&A[(size_t)(m0 + r1s) * K + k0 + c1s], &As[e1]);
    async_cp16(&Bt[(size_t)(n0 + r0s) * K + k0 + c0s], &Bs[e0]);
    async_cp16(&Bt[(size_t)(n0 + r1s) * K + k0 + c1s], &Bs[e1]);
    __syncthreads();
    bf16x8 af[TM], bfr[4];
#pragma unroll
    for (int t = 0; t < TM; t++)
      af[t] = *(const bf16x8*)&As[(wm + t * 16 + l15) * 32 + quad * 8];
#pragma unroll
    for (int t = 0; t < 4; t++)
      bfr[t] = *(const bf16x8*)&Bs[(wn + t * 16 + l15) * 32 + quad * 8];
#pragma unroll
    for (int tm = 0; tm < TM; tm++)
#pragma unroll
      for (int tn = 0; tn < 4; tn++)
        acc[tm][tn] = __builtin_amdgcn_mfma_f32_16x16x32_bf16(af[tm], bfr[tn], acc[tm][tn], 0, 0, 0);
  }

#pragma unroll
  for (int tm = 0; tm < TM; tm++) {
    const int row = m0 + wm + tm * 16 + quad * 4;
#pragma unroll
    for (int tn = 0; tn < 4; tn++) {
      const int col = n0 + wn + tn * 16 + l15;
      const float bv = bias[col];
#pragma unroll
      for (int rr = 0; rr < 4; rr++) {
        if constexpr (OUTF)
          ((float*)Cv)[(size_t)(row + rr) * N + col] = acc[tm][tn][rr] + bv;
        else
          ((ushort_t*)Cv)[(size_t)(row + rr) * N + col] = f2b_hw(acc[tm][tn][rr] + bv);
      }
    }
  }
}

// ---------- MFMA flash attention (S^T / O^T form), causal ----------
// Block j in [0,8): sequentially processes q-tile j (2j+2 key-tiles) then
// q-tile 15-j (32-2j) -> uniform 34 iters/block, all 4 waves compute ~every
// iter (contiguous 128-q tile per phase, wave spread <= 1 iter).
// Double-buffered K/V, ONE barrier per iter; K staged via global_load_lds
// (lane-linear m97 layout); V via 2-deep register prefetch + perm pack.
#define PSTR 72  // Vt/Plds row stride: 144 B, 16B-aligned

__device__ __forceinline__ void commit_v(ushort_t* __restrict__ vt, int vd0, int vpair,
                                         uint4 pV0, uint4 pV1) {
  union { uint32_t u[4]; uint4 v; } a, c;
  a.v = pV0; c.v = pV1;
#pragma unroll
  for (int j = 0; j < 8; j++) {
    uint32_t pk = __builtin_amdgcn_perm(c.u[j >> 1], a.u[j >> 1],
                                        (j & 1) ? 0x07060302u : 0x05040100u);
    *(uint32_t*)&vt[(vd0 + j) * PSTR + 2 * vpair] = pk;
  }
}

__global__ __launch_bounds__(256) void attn_mfma_k(const ushort_t* __restrict__ qkv,
                                                   ushort_t* __restrict__ y) {
  __shared__ ushort_t Ksm[2][2][64 * 32];  // [buf][d-half][key*32]
  __shared__ ushort_t Vt[2][64 * PSTR];    // [buf][d][key]
  __shared__ ushort_t Plds[4][32 * PSTR];  // per-wave [q_local][key]

  const int jj = blockIdx.x;  // 0..7
  const int h = blockIdx.y, b = blockIdx.z;
  const int tid = threadIdx.x;
  const int w = tid >> 6, lane = tid & 63;
  const int quad = lane >> 4, l15 = lane & 15;

  // staging maps
  const int e0 = tid * 8;                       // K: lane-linear 16B chunks
  const int k_key = e0 >> 5, k_col = e0 & 31;
  const int vpair = tid & 31, vd0 = (tid >> 5) * 8;
  const ushort_t* kbase = qkv + ((size_t)(b * T_SEQ) + k_key) * C3 + CEMB + h * HDIM + k_col;
  const ushort_t* vbase = qkv + ((size_t)(b * T_SEQ) + 2 * vpair) * C3 + 2 * CEMB + h * HDIM + vd0;
  const size_t step = (size_t)64 * C3;

  // hoisted LDS offsets
  int koff[4], voff[4], poffR[2], poffW[2];
#pragma unroll
  for (int m = 0; m < 4; m++) koff[m] = (m * 16 + l15) * 32 + quad * 8;
#pragma unroll
  for (int nd = 0; nd < 4; nd++) voff[nd] = (nd * 16 + l15) * PSTR + quad * 8;
#pragma unroll
  for (int n = 0; n < 2; n++) {
    poffR[n] = (n * 16 + l15) * PSTR + quad * 8;
    poffW[n] = (n * 16 + l15) * PSTR + quad * 4;
  }

  const float C2 = 0.18033688011112042f;  // 0.125 * log2(e)

  for (int ph = 0; ph < 2; ++ph) {
    const int qt = ph ? (15 - jj) : jj;
    const int nkt = 2 * qt + 2;
    const int qw = qt * 128 + w * 32;

    // Q fragments (B-operand): [q-subtile][d-half]
    bf16x8 qB[2][2];
#pragma unroll
    for (int n = 0; n < 2; n++)
#pragma unroll
      for (int kb = 0; kb < 2; kb++)
        qB[n][kb] = *(const bf16x8*)&qkv[((size_t)(b * T_SEQ + qw + n * 16 + l15)) * C3 +
                                         h * HDIM + kb * 32 + quad * 8];

    f32x4 o2[4][2] = {};  // O^T: [d-sub][q-sub]
    float m_i[2] = {-3e38f, -3e38f}, l_i[2] = {0.f, 0.f};

    __syncthreads();  // previous phase's LDS reads complete before restaging

    // ---- prologue: stage tile 0, prefetch V tile 1 ----
    const ushort_t* kp = kbase;
    const ushort_t* vp = vbase;
    uint4 pV0 = *(const uint4*)vp, pV1 = *(const uint4*)(vp + C3);
    async_cp16(kp, &Ksm[0][0][e0]);
    async_cp16(kp + 32, &Ksm[0][1][e0]);
    commit_v(Vt[0], vd0, vpair, pV0, pV1);
    vp += step;
    pV0 = *(const uint4*)vp; pV1 = *(const uint4*)(vp + C3);

    for (int kt = 0; kt < nkt; ++kt) {
      __syncthreads();  // tile kt staged (barrier drains vmcnt + lgkmcnt)
      // ---- stage tile kt+1 into the other buffer (overlaps compute) ----
      if (kt + 1 < nkt) {
        const int nb = (kt + 1) & 1;
        kp += step;
        async_cp16(kp, &Ksm[nb][0][e0]);
        async_cp16(kp + 32, &Ksm[nb][1][e0]);
        commit_v(Vt[nb], vd0, vpair, pV0, pV1);
        if (kt + 2 < nkt) {
          vp += step;
          pV0 = *(const uint4*)vp; pV1 = *(const uint4*)(vp + C3);
        }
      }
      const int cb = kt & 1;

      if (kt * 64 <= qw + 31) {
        // ---- S^T = K*Q^T ----
        bf16x8 kA[4][2];
#pragma unroll
        for (int m = 0; m < 4; m++) {
          kA[m][0] = *(const bf16x8*)&Ksm[cb][0][koff[m]];
          kA[m][1] = *(const bf16x8*)&Ksm[cb][1][koff[m]];
        }
        f32x4 st[4][2] = {};  // [key-sub][q-sub]
#pragma unroll
        for (int m = 0; m < 4; m++)
#pragma unroll
          for (int n = 0; n < 2; n++) {
            st[m][n] = __builtin_amdgcn_mfma_f32_16x16x32_bf16(kA[m][0], qB[n][0], st[m][n], 0, 0, 0);
            st[m][n] = __builtin_amdgcn_mfma_f32_16x16x32_bf16(kA[m][1], qB[n][1], st[m][n], 0, 0, 0);
          }

        // ---- causal mask (near diagonal only) ----
        if (kt * 64 + 63 > qw) {
#pragma unroll
          for (int m = 0; m < 4; m++)
#pragma unroll
            for (int r = 0; r < 4; r++) {
              const int keyg = kt * 64 + m * 16 + quad * 4 + r;
#pragma unroll
              for (int n = 0; n < 2; n++) {
                const int qg = qw + n * 16 + l15;
                if (keyg > qg) st[m][n][r] = -3e38f;
              }
            }
        }

        // ---- online softmax (q on l15; keys in-lane + cross-quad) ----
        float al[2];
#pragma unroll
        for (int n = 0; n < 2; n++) {
          float mx = st[0][n][0];
#pragma unroll
          for (int m = 0; m < 4; m++)
#pragma unroll
            for (int r = 0; r < 4; r++) mx = fmaxf(mx, st[m][n][r]);
          mx = fmaxf(mx, __shfl_xor(mx, 16, 64));
          mx = fmaxf(mx, __shfl_xor(mx, 32, 64));
          const float mn = fmaxf(m_i[n], mx);
          al[n] = exp2f((m_i[n] - mn) * C2);
          m_i[n] = mn;
          const float mnc = mn * C2;
          float ls = 0.f;
#pragma unroll
          for (int m = 0; m < 4; m++)
#pragma unroll
            for (int r = 0; r < 4; r++) {
              float p = exp2f(fmaf(st[m][n][r], C2, -mnc));
              st[m][n][r] = p;
              ls += p;
            }
          ls += __shfl_xor(ls, 16, 64);
          ls += __shfl_xor(ls, 32, 64);
          l_i[n] = l_i[n] * al[n] + ls;
        }

        // ---- P -> LDS (packed b64) + O^T rescale (alpha per-lane) ----
#pragma unroll
        for (int n = 0; n < 2; n++) {
#pragma unroll
          for (int m = 0; m < 4; m++) {
            uint2 pk;
            pk.x = pkbf16(st[m][n][0], st[m][n][1]);
            pk.y = pkbf16(st[m][n][2], st[m][n][3]);
            *(uint2*)&Plds[w][poffW[n] + m * 16] = pk;
          }
#pragma unroll
          for (int nd = 0; nd < 4; nd++)
#pragma unroll
            for (int r = 0; r < 4; r++) o2[nd][n][r] *= al[n];
        }

        // in-wave DS ordering: P writes committed before cross-lane reads
        asm volatile("s_waitcnt lgkmcnt(0)" ::: "memory");

        // ---- O^T += V^T * P^T  (A=V^T, B=P) ----
        bf16x8 ap[2][2], bv[4][2];
#pragma unroll
        for (int n = 0; n < 2; n++)
#pragma unroll
          for (int kb = 0; kb < 2; kb++)
            ap[n][kb] = *(const bf16x8*)&Plds[w][poffR[n] + kb * 32];
#pragma unroll
        for (int nd = 0; nd < 4; nd++)
#pragma unroll
          for (int kb = 0; kb < 2; kb++)
            bv[nd][kb] = *(const bf16x8*)&Vt[cb][voff[nd] + kb * 32];
#pragma unroll
        for (int nd = 0; nd < 4; nd++)
#pragma unroll
          for (int n = 0; n < 2; n++) {
            o2[nd][n] = __builtin_amdgcn_mfma_f32_16x16x32_bf16(bv[nd][0], ap[n][0], o2[nd][n], 0, 0, 0);
            o2[nd][n] = __builtin_amdgcn_mfma_f32_16x16x32_bf16(bv[nd][1], ap[n][1], o2[nd][n], 0, 0, 0);
          }
      }
    }

    // ---- epilogue: y[q][h*64+d] = O^T[d][q] / l, packed b64 stores ----
#pragma unroll
    for (int n = 0; n < 2; n++) {
      const float inv = 1.0f / l_i[n];
      const int qg = qw + n * 16 + l15;
      ushort_t* yp = y + ((size_t)(b * T_SEQ + qg)) * CEMB + h * HDIM + quad * 4;
#pragma unroll
      for (int nd = 0; nd < 4; nd++) {
        uint2 pk;
        pk.x = pkbf16(o2[nd][n][0] * inv, o2[nd][n][1] * inv);
        pk.y = pkbf16(o2[nd][n][2] * inv, o2[nd][n][3] * inv);
        *(uint2*)(yp + nd * 16) = pk;
      }
    }
  }
}

// ---------- launcher ----------
extern "C" void kernel_launch(void* const* d_in, const int* in_sizes, int n_in,
                              void* d_out, int out_size, void* d_ws, size_t ws_size,
                              hipStream_t stream) {
  const float* x      = (const float*)d_in[0];  // [4,2048,768] fp32
  const float* w_attn = (const float*)d_in[1];  // [768,2304]
  const float* b_attn = (const float*)d_in[2];  // [2304]
  const float* w_proj = (const float*)d_in[3];  // [768,768]
  const float* b_proj = (const float*)d_in[4];  // [768]
  float* out = (float*)d_out;                   // [4,2048,768] fp32

  char* ws = (char*)d_ws;
  ushort_t* qkv = (ushort_t*)ws;                          // 8192*2304 bf16
  ushort_t* y   = qkv + (size_t)8192 * 2304;              // 8192*768
  ushort_t* xb  = y + (size_t)8192 * 768;                 // 8192*768 bf16 x
  ushort_t* wT  = xb + (size_t)8192 * 768;                // 2304*768 (w_attn^T)
  ushort_t* wpT = wT + (size_t)2304 * 768;                // 768*768  (w_proj^T)

  // fused prep: cvt x + transpose both weights (1 dispatch instead of 3)
  prep_k<<<5376, 256, 0, stream>>>(x, xb, w_attn, wT, w_proj, wpT);

  // qkv = x @ w_attn + b_attn   (M=8192, N=2304, K=768), bf16 out
  gemm_bt<false, 128><<<dim3(C3 / 128, 8192 / 128), 256, 0, stream>>>(xb, wT, b_attn, qkv, 8192, C3, CEMB);

  // MFMA flash attention -> y [B,T,C] bf16; paired q-tiles, uniform work
  attn_mfma_k<<<dim3(8, NHEAD, BATCH), 256, 0, stream>>>(qkv, y);

  // out = y @ w_proj + b_proj   (M=8192, N=768, K=768), fp32 out
  gemm_bt<true, 64><<<dim3(CEMB / 128, 8192 / 64), 256, 0, stream>>>(y, wpT, b_proj, out, 8192, CEMB, CEMB);
}

// Round 10
// 231.927 us; speedup vs baseline: 1.2568x; 1.1079x over previous
//
#include <hip/hip_runtime.h>
#include <stdint.h>

typedef unsigned short ushort_t;

#define T_SEQ 2048
#define BATCH 4
#define NHEAD 12
#define CEMB 768
#define HDIM 64
#define C3 2304

// ---------- bf16 helpers (HW convert, RNE) ----------
__device__ __forceinline__ ushort_t f2b_hw(float f) {
  union { __bf16 h; ushort_t u; } p;
  p.h = (__bf16)f;
  return p.u;
}
__device__ __forceinline__ uint32_t pkbf16(float lo, float hi) {
  union { __bf16 h[2]; uint32_t u; } p;
  p.h[0] = (__bf16)lo; p.h[1] = (__bf16)hi;
  return p.u;
}

// ---------- async global->LDS 16B ----------
typedef __attribute__((address_space(3))) unsigned int lds_u32_t;
typedef const __attribute__((address_space(1))) unsigned int glb_u32_t;
__device__ __forceinline__ void async_cp16(const void* g, void* l) {
  __builtin_amdgcn_global_load_lds((glb_u32_t*)g, (lds_u32_t*)l, 16, 0, 0);
}

// ---------- fused prep: cvt x -> bf16; transpose+cvt both weights ----------
__global__ __launch_bounds__(256) void prep_k(const float* __restrict__ x, ushort_t* __restrict__ xb,
                                              const float* __restrict__ wa, ushort_t* __restrict__ wT,
                                              const float* __restrict__ wp, ushort_t* __restrict__ wpT) {
  const int blk = blockIdx.x;
  const int tid = threadIdx.x;
  if (blk < 3072) {
    const int i = blk * 256 + tid;
    float4 a = ((const float4*)x)[2 * i];
    float4 b = ((const float4*)x)[2 * i + 1];
    uint4 v;
    v.x = pkbf16(a.x, a.y); v.y = pkbf16(a.z, a.w);
    v.z = pkbf16(b.x, b.y); v.w = pkbf16(b.z, b.w);
    ((uint4*)xb)[i] = v;
    return;
  }
  __shared__ ushort_t tile[32][33];
  const float* in; ushort_t* out; int R, C, bx, by;
  if (blk < 4800) {
    const int t = blk - 3072;
    in = wa; out = wT; R = CEMB; C = C3;
    bx = t % 72; by = t / 72;
  } else {
    const int t = blk - 4800;
    in = wp; out = wpT; R = CEMB; C = CEMB;
    bx = t % 24; by = t / 24;
  }
  const int tx = tid & 31, ty = tid >> 5;
  const int c0 = bx * 32, r0 = by * 32;
  for (int i = ty; i < 32; i += 8)
    tile[i][tx] = f2b_hw(in[(size_t)(r0 + i) * C + c0 + tx]);
  __syncthreads();
  for (int i = ty; i < 32; i += 8)
    out[(size_t)(c0 + i) * R + r0 + tx] = tile[tx][i];
}

// ---------- MFMA GEMM, BK=64 (two 32-col panes): C = A * Bt^T + bias ----------
typedef __bf16 bf16x8 __attribute__((ext_vector_type(8)));
typedef float f32x4 __attribute__((ext_vector_type(4)));

template <bool OUTF, int BM>  // BM = M-tile (128 or 64), N-tile fixed 128
__global__ __launch_bounds__(256) void gemm_bt(const ushort_t* __restrict__ A,
                                               const ushort_t* __restrict__ Bt,
                                               const float* __restrict__ bias,
                                               void* __restrict__ Cv,
                                               int M, int N, int K) {
  constexpr int TM = BM / 32;
  __shared__ ushort_t As[2 * BM * 32];    // [pane][row][32]
  __shared__ ushort_t Bs[2 * 128 * 32];
  const int tid = threadIdx.x;
  const int m0 = blockIdx.y * BM, n0 = blockIdx.x * 128;
  const int wid = tid >> 6, lane = tid & 63;
  const int quad = lane >> 4, l15 = lane & 15;
  const int wm = (wid >> 1) * (BM / 2), wn = (wid & 1) * 64;
  f32x4 acc[TM][4] = {};

  const int e0 = tid * 8;               // lane-linear 16B chunks within a pane
  const int r0s = e0 >> 5, c0s = e0 & 31;
  const int e1 = e0 + 2048;
  const int r1s = e1 >> 5, c1s = e1 & 31;

  for (int k0 = 0; k0 < K; k0 += 64) {
    __syncthreads();
#pragma unroll
    for (int p = 0; p < 2; p++) {
      const int kc = k0 + p * 32;
      async_cp16(&A[(size_t)(m0 + r0s) * K + kc + c0s], &As[p * BM * 32 + e0]);
      if constexpr (BM == 128)
        async_cp16(&A[(size_t)(m0 + r1s) * K + kc + c1s], &As[p * BM * 32 + e1]);
      async_cp16(&Bt[(size_t)(n0 + r0s) * K + kc + c0s], &Bs[p * 128 * 32 + e0]);
      async_cp16(&Bt[(size_t)(n0 + r1s) * K + kc + c1s], &Bs[p * 128 * 32 + e1]);
    }
    __syncthreads();
    bf16x8 af[TM][2], bfr[4][2];
#pragma unroll
    for (int t = 0; t < TM; t++)
#pragma unroll
      for (int p = 0; p < 2; p++)
        af[t][p] = *(const bf16x8*)&As[p * BM * 32 + (wm + t * 16 + l15) * 32 + quad * 8];
#pragma unroll
    for (int t = 0; t < 4; t++)
#pragma unroll
      for (int p = 0; p < 2; p++)
        bfr[t][p] = *(const bf16x8*)&Bs[p * 128 * 32 + (wn + t * 16 + l15) * 32 + quad * 8];
#pragma unroll
    for (int p = 0; p < 2; p++)
#pragma unroll
      for (int tm = 0; tm < TM; tm++)
#pragma unroll
        for (int tn = 0; tn < 4; tn++)
          acc[tm][tn] = __builtin_amdgcn_mfma_f32_16x16x32_bf16(af[tm][p], bfr[tn][p], acc[tm][tn], 0, 0, 0);
  }

#pragma unroll
  for (int tm = 0; tm < TM; tm++) {
    const int row = m0 + wm + tm * 16 + quad * 4;
#pragma unroll
    for (int tn = 0; tn < 4; tn++) {
      const int col = n0 + wn + tn * 16 + l15;
      const float bv = bias[col];
#pragma unroll
      for (int rr = 0; rr < 4; rr++) {
        if constexpr (OUTF)
          ((float*)Cv)[(size_t)(row + rr) * N + col] = acc[tm][tn][rr] + bv;
        else
          ((ushort_t*)Cv)[(size_t)(row + rr) * N + col] = f2b_hw(acc[tm][tn][rr] + bv);
      }
    }
  }
}

// ---------- MFMA flash attention (S^T / O^T form), causal ----------
// Block j in [0,16): q-tile j (j+1 key-tiles) then q-tile 31-j (32-j)
// -> uniform 33 iters/block. 64-q tiles, 4 waves x 16 q: every wave active
// every iter (nkt = qt+1 exactly). Double-buffered K/V, one barrier/iter.
#define PSTR 72  // Vt/Plds row stride: 144 B, 16B-aligned

__device__ __forceinline__ void commit_v(ushort_t* __restrict__ vt, int vd0, int vpair,
                                         uint4 pV0, uint4 pV1) {
  union { uint32_t u[4]; uint4 v; } a, c;
  a.v = pV0; c.v = pV1;
#pragma unroll
  for (int j = 0; j < 8; j++) {
    uint32_t pk = __builtin_amdgcn_perm(c.u[j >> 1], a.u[j >> 1],
                                        (j & 1) ? 0x07060302u : 0x05040100u);
    *(uint32_t*)&vt[(vd0 + j) * PSTR + 2 * vpair] = pk;
  }
}

__global__ __launch_bounds__(256) void attn_mfma_k(const ushort_t* __restrict__ qkv,
                                                   ushort_t* __restrict__ y) {
  __shared__ ushort_t Ksm[2][2][64 * 32];  // [buf][d-half][key*32]
  __shared__ ushort_t Vt[2][64 * PSTR];    // [buf][d][key]
  __shared__ ushort_t Plds[4][16 * PSTR];  // per-wave [q_local(16)][key]

  const int jj = blockIdx.x;  // 0..15
  const int h = blockIdx.y, b = blockIdx.z;
  const int tid = threadIdx.x;
  const int w = tid >> 6, lane = tid & 63;
  const int quad = lane >> 4, l15 = lane & 15;

  // staging maps
  const int e0 = tid * 8;                       // K: lane-linear 16B chunks
  const int vpair = tid & 31, vd0 = (tid >> 5) * 8;
  const ushort_t* kbase = qkv + ((size_t)(b * T_SEQ) + (e0 >> 5)) * C3 + CEMB + h * HDIM + (e0 & 31);
  const ushort_t* vbase = qkv + ((size_t)(b * T_SEQ) + 2 * vpair) * C3 + 2 * CEMB + h * HDIM + vd0;
  const size_t step = (size_t)64 * C3;

  // hoisted LDS offsets
  int koff[4], voff[4];
#pragma unroll
  for (int m = 0; m < 4; m++) koff[m] = (m * 16 + l15) * 32 + quad * 8;
#pragma unroll
  for (int nd = 0; nd < 4; nd++) voff[nd] = (nd * 16 + l15) * PSTR + quad * 8;
  const int poffR = l15 * PSTR + quad * 8;
  const int poffW = l15 * PSTR + quad * 4;
  const int qloc = 16 * w + l15;  // wave-local q row (for mask)

  const float C2 = 0.18033688011112042f;  // 0.125 * log2(e)

  for (int ph = 0; ph < 2; ++ph) {
    const int qt = ph ? (31 - jj) : jj;   // 64-q tile index
    const int nkt = qt + 1;
    const int qw = qt * 64 + w * 16;      // wave's first q row

    // Q fragments (B-operand): [d-half]; rows qw + l15 = wave's 16 q
    bf16x8 qB[2];
#pragma unroll
    for (int kb = 0; kb < 2; kb++)
      qB[kb] = *(const bf16x8*)&qkv[((size_t)(b * T_SEQ + qw + l15)) * C3 +
                                    h * HDIM + kb * 32 + quad * 8];

    f32x4 o2[4] = {};  // O^T: [d-sub], row=d(quad*4+r), col=q(l15)
    float m_i = -3e38f, l_i = 0.f;

    __syncthreads();  // previous phase's LDS reads complete before restaging

    // ---- prologue: stage tile 0, prefetch V tile 1 ----
    const ushort_t* kp = kbase;
    const ushort_t* vp = vbase;
    uint4 pV0 = *(const uint4*)vp, pV1 = *(const uint4*)(vp + C3);
    async_cp16(kp, &Ksm[0][0][e0]);
    async_cp16(kp + 32, &Ksm[0][1][e0]);
    commit_v(Vt[0], vd0, vpair, pV0, pV1);
    vp += step;
    pV0 = *(const uint4*)vp; pV1 = *(const uint4*)(vp + C3);

    for (int kt = 0; kt < nkt; ++kt) {
      __syncthreads();  // tile kt staged (barrier drains vmcnt + lgkmcnt)
      // ---- stage tile kt+1 into the other buffer (overlaps compute) ----
      if (kt + 1 < nkt) {
        const int nb = (kt + 1) & 1;
        kp += step;
        async_cp16(kp, &Ksm[nb][0][e0]);
        async_cp16(kp + 32, &Ksm[nb][1][e0]);
        commit_v(Vt[nb], vd0, vpair, pV0, pV1);
        if (kt + 2 < nkt) {
          vp += step;
          pV0 = *(const uint4*)vp; pV1 = *(const uint4*)(vp + C3);
        }
      }
      const int cb = kt & 1;

      // ---- S^T = K*Q^T ----
      bf16x8 kA[4][2];
#pragma unroll
      for (int m = 0; m < 4; m++) {
        kA[m][0] = *(const bf16x8*)&Ksm[cb][0][koff[m]];
        kA[m][1] = *(const bf16x8*)&Ksm[cb][1][koff[m]];
      }
      f32x4 st[4] = {};  // [key-sub]; col=q(l15), row=key(quad*4+r)
#pragma unroll
      for (int m = 0; m < 4; m++) {
        st[m] = __builtin_amdgcn_mfma_f32_16x16x32_bf16(kA[m][0], qB[0], st[m], 0, 0, 0);
        st[m] = __builtin_amdgcn_mfma_f32_16x16x32_bf16(kA[m][1], qB[1], st[m], 0, 0, 0);
      }

      // ---- causal mask: only the diagonal tile ----
      if (kt == qt) {
#pragma unroll
        for (int m = 0; m < 4; m++)
#pragma unroll
          for (int r = 0; r < 4; r++)
            if (m * 16 + quad * 4 + r > qloc) st[m][r] = -3e38f;
      }

      // ---- online softmax (q on l15; keys in-lane + cross-quad) ----
      float mx = st[0][0];
#pragma unroll
      for (int m = 0; m < 4; m++)
#pragma unroll
        for (int r = 0; r < 4; r++) mx = fmaxf(mx, st[m][r]);
      mx = fmaxf(mx, __shfl_xor(mx, 16, 64));
      mx = fmaxf(mx, __shfl_xor(mx, 32, 64));
      const float mn = fmaxf(m_i, mx);
      const float al = exp2f((m_i - mn) * C2);
      m_i = mn;
      const float mnc = mn * C2;
      float ls = 0.f;
#pragma unroll
      for (int m = 0; m < 4; m++)
#pragma unroll
        for (int r = 0; r < 4; r++) {
          float p = exp2f(fmaf(st[m][r], C2, -mnc));
          st[m][r] = p;
          ls += p;
        }
      ls += __shfl_xor(ls, 16, 64);
      ls += __shfl_xor(ls, 32, 64);
      l_i = l_i * al + ls;

      // ---- P -> LDS (packed b64) + O^T rescale (alpha per-lane) ----
#pragma unroll
      for (int m = 0; m < 4; m++) {
        uint2 pk;
        pk.x = pkbf16(st[m][0], st[m][1]);
        pk.y = pkbf16(st[m][2], st[m][3]);
        *(uint2*)&Plds[w][poffW + m * 16] = pk;
      }
#pragma unroll
      for (int nd = 0; nd < 4; nd++)
#pragma unroll
        for (int r = 0; r < 4; r++) o2[nd][r] *= al;

      // in-wave DS ordering: P writes committed before cross-lane reads
      asm volatile("s_waitcnt lgkmcnt(0)" ::: "memory");

      // ---- O^T += V^T * P^T  (A=V^T, B=P) ----
      bf16x8 ap[2], bv[4][2];
#pragma unroll
      for (int kb = 0; kb < 2; kb++)
        ap[kb] = *(const bf16x8*)&Plds[w][poffR + kb * 32];
#pragma unroll
      for (int nd = 0; nd < 4; nd++)
#pragma unroll
        for (int kb = 0; kb < 2; kb++)
          bv[nd][kb] = *(const bf16x8*)&Vt[cb][voff[nd] + kb * 32];
#pragma unroll
      for (int nd = 0; nd < 4; nd++) {
        o2[nd] = __builtin_amdgcn_mfma_f32_16x16x32_bf16(bv[nd][0], ap[0], o2[nd], 0, 0, 0);
        o2[nd] = __builtin_amdgcn_mfma_f32_16x16x32_bf16(bv[nd][1], ap[1], o2[nd], 0, 0, 0);
      }
    }

    // ---- epilogue: y[q][h*64+d] = O^T[d][q] / l, packed b64 stores ----
    {
      const float inv = 1.0f / l_i;
      const int qg = qw + l15;
      ushort_t* yp = y + ((size_t)(b * T_SEQ + qg)) * CEMB + h * HDIM + quad * 4;
#pragma unroll
      for (int nd = 0; nd < 4; nd++) {
        uint2 pk;
        pk.x = pkbf16(o2[nd][0] * inv, o2[nd][1] * inv);
        pk.y = pkbf16(o2[nd][2] * inv, o2[nd][3] * inv);
        *(uint2*)(yp + nd * 16) = pk;
      }
    }
  }
}

// ---------- launcher ----------
extern "C" void kernel_launch(void* const* d_in, const int* in_sizes, int n_in,
                              void* d_out, int out_size, void* d_ws, size_t ws_size,
                              hipStream_t stream) {
  const float* x      = (const float*)d_in[0];  // [4,2048,768] fp32
  const float* w_attn = (const float*)d_in[1];  // [768,2304]
  const float* b_attn = (const float*)d_in[2];  // [2304]
  const float* w_proj = (const float*)d_in[3];  // [768,768]
  const float* b_proj = (const float*)d_in[4];  // [768]
  float* out = (float*)d_out;                   // [4,2048,768] fp32

  char* ws = (char*)d_ws;
  ushort_t* qkv = (ushort_t*)ws;                          // 8192*2304 bf16
  ushort_t* y   = qkv + (size_t)8192 * 2304;              // 8192*768
  ushort_t* xb  = y + (size_t)8192 * 768;                 // 8192*768 bf16 x
  ushort_t* wT  = xb + (size_t)8192 * 768;                // 2304*768 (w_attn^T)
  ushort_t* wpT = wT + (size_t)2304 * 768;                // 768*768  (w_proj^T)

  // fused prep: cvt x + transpose both weights
  prep_k<<<5376, 256, 0, stream>>>(x, xb, w_attn, wT, w_proj, wpT);

  // qkv = x @ w_attn + b_attn   (M=8192, N=2304, K=768), bf16 out, BK=64
  gemm_bt<false, 128><<<dim3(C3 / 128, 8192 / 128), 256, 0, stream>>>(xb, wT, b_attn, qkv, 8192, C3, CEMB);

  // MFMA flash attention -> y [B,T,C] bf16; 64-q paired tiles, 768 blocks
  attn_mfma_k<<<dim3(16, NHEAD, BATCH), 256, 0, stream>>>(qkv, y);

  // out = y @ w_proj + b_proj   (M=8192, N=768, K=768), fp32 out, BK=64
  gemm_bt<true, 64><<<dim3(CEMB / 128, 8192 / 64), 256, 0, stream>>>(y, wpT, b_proj, out, 8192, CEMB, CEMB);
}